// Round 9
// baseline (1927.885 us; speedup 1.0000x reference)
//
#include <hip/hip_runtime.h>

#define M_TETS 10240
#define N_NODES 2048
#define NPH 150
#define NBLK 32
#define NTHR 320
#define SPIN_CAP 50000000

// ws float offsets
#define OFF_VAL   12288            // blk6: 6*2048 floats at 0
#define OFF_GDOT  36864            // val: 3 bufs x 2048 x 4
#define OFF_SLOT  37120            // gdot: 2 sets x 2 comps x 64
#define WS_WORDS  37152            // + 32 flag words

// log(500), log(10000)
__device__ __constant__ float LOG_A_MIN_C = 6.2146080984221914f;
__device__ __constant__ float LOG_A_MAX_C = 9.2103403719761836f;

__device__ __forceinline__ void rel_fence() { __builtin_amdgcn_fence(__ATOMIC_RELEASE, "agent"); }
__device__ __forceinline__ void acq_fence() { __builtin_amdgcn_fence(__ATOMIC_ACQUIRE, "agent"); }
__device__ __forceinline__ unsigned aldu(const unsigned* p) {
    return __hip_atomic_load(p, __ATOMIC_RELAXED, __HIP_MEMORY_SCOPE_AGENT);
}
__device__ __forceinline__ float aldf(const float* p) {
    return __hip_atomic_load(p, __ATOMIC_RELAXED, __HIP_MEMORY_SCOPE_AGENT);
}
__device__ __forceinline__ void astf(float* p, float v) {
    __hip_atomic_store(p, v, __ATOMIC_RELAXED, __HIP_MEMORY_SCOPE_AGENT);
}
__device__ __forceinline__ void astu(unsigned* p, unsigned v) {
    __hip_atomic_store(p, v, __ATOMIC_RELAXED, __HIP_MEMORY_SCOPE_AGENT);
}

// Distributed-flag barrier: one publish per block, 32-lane parallel poll.
__device__ __forceinline__ void flag_bar(unsigned* slots, unsigned tgt) {
    rel_fence();
    __syncthreads();
    if (threadIdx.x == 0) astu(&slots[blockIdx.x], tgt);
    if (threadIdx.x < NBLK) {
        int guard = 0;
        while (aldu(&slots[threadIdx.x]) < tgt && ++guard < SPIN_CAP) {}
    }
    __syncthreads();
    acq_fence();
}

__device__ __forceinline__ void bfly2(float& a, float& b) {
#pragma unroll
    for (int off = 32; off > 0; off >>= 1) {
        a += __shfl_xor(a, off);
        b += __shfl_xor(b, off);
    }
}

// symmetric 3x3 apply: s6 = [00,01,02,11,12,22]
__device__ __forceinline__ void sym_apply(const float* s6, const float* v, float* out) {
    out[0] = s6[0]*v[0] + s6[1]*v[1] + s6[2]*v[2];
    out[1] = s6[1]*v[0] + s6[3]*v[1] + s6[4]*v[2];
    out[2] = s6[2]*v[0] + s6[4]*v[1] + s6[5]*v[2];
}

__device__ __forceinline__ void sym_inv(const float* s, float* o) {
    float a = s[0], b = s[1], c = s[2], d = s[3], e = s[4], f = s[5];
    float C00 = d*f - e*e, C01 = c*e - b*f, C02 = b*e - c*d;
    float id = 1.0f / (a*C00 + b*C01 + c*C02);
    o[0] = C00*id; o[1] = C01*id; o[2] = C02*id;
    o[3] = (a*f - c*c)*id; o[4] = (b*c - a*e)*id; o[5] = (a*d - b*b)*id;
}

__global__ void __launch_bounds__(NTHR, 1) pcg_kernel(
    const float* __restrict__ theta, const float* __restrict__ delta,
    const float* __restrict__ ra, const float* __restrict__ rs, const float* __restrict__ rv,
    const float* __restrict__ vol, const float* __restrict__ bvec,
    const int* __restrict__ tets, const int* __restrict__ boundary,
    float* __restrict__ xout, float* __restrict__ ws)
{
    const int tid = blockIdx.x * NTHR + threadIdx.x;   // element id, 10240 total
    const int lane = threadIdx.x & 63;
    __shared__ float sd[2];

    float*    blk6  = ws;
    float*    val   = ws + OFF_VAL;
    float*    gdot  = ws + OFF_GDOT;
    unsigned* slots = (unsigned*)(ws + OFF_SLOT);

    // ---- element data -> registers (ws pre-zeroed by hipMemsetAsync) ----
    float A[3][12], S[3][12], V[12];
    int nd4[4];
    float cae, cse, cve;
    {
        const int e = tid;
#pragma unroll
        for (int a = 0; a < 3; a++)
#pragma unroll
            for (int i = 0; i < 12; i++) {
                A[a][i] = ra[e * 36 + a * 12 + i];
                S[a][i] = rs[e * 36 + a * 12 + i];
            }
#pragma unroll
        for (int i = 0; i < 12; i++) V[i] = rv[e * 12 + i];
        const int4 t = reinterpret_cast<const int4*>(tets)[e];
        nd4[0] = t.x; nd4[1] = t.y; nd4[2] = t.z; nd4[3] = t.w;
        float la = theta[0] + delta[e];
        la = fminf(fmaxf(la, LOG_A_MIN_C), LOG_A_MAX_C);
        float al = expf(la);
        float v = vol[e];
        cae = v * al; cse = 2.0f * v * al; cve = 8.0f * v * al;
    }

    auto matvec = [&](const float* pe, float* y) {
#pragma unroll
        for (int t = 0; t < 12; t++) y[t] = 0.f;
#pragma unroll
        for (int a = 0; a < 3; a++) {
            float qa = 0.f, qs = 0.f;
#pragma unroll
            for (int t = 0; t < 12; t++) { qa += A[a][t] * pe[t]; qs += S[a][t] * pe[t]; }
            qa *= cae; qs *= cse;
#pragma unroll
            for (int t = 0; t < 12; t++) y[t] += qa * A[a][t] + qs * S[a][t];
        }
        float qv = 0.f;
#pragma unroll
        for (int t = 0; t < 12; t++) qv += V[t] * pe[t];
        qv *= cve;
#pragma unroll
        for (int t = 0; t < 12; t++) y[t] += qv * V[t];
    };

    // ---- S1: accumulate symmetric per-node 3x3 blocks of K ----
#pragma unroll
    for (int k = 0; k < 4; k++) {
        float b6[6] = {0,0,0,0,0,0};
#pragma unroll
        for (int a = 0; a < 3; a++) {
            float x0 = A[a][3*k], x1 = A[a][3*k+1], x2 = A[a][3*k+2];
            float s0 = S[a][3*k], s1 = S[a][3*k+1], s2 = S[a][3*k+2];
            b6[0] += cae*x0*x0 + cse*s0*s0;
            b6[1] += cae*x0*x1 + cse*s0*s1;
            b6[2] += cae*x0*x2 + cse*s0*s2;
            b6[3] += cae*x1*x1 + cse*s1*s1;
            b6[4] += cae*x1*x2 + cse*s1*s2;
            b6[5] += cae*x2*x2 + cse*s2*s2;
        }
        float v0 = V[3*k], v1 = V[3*k+1], v2 = V[3*k+2];
        b6[0] += cve*v0*v0; b6[1] += cve*v0*v1; b6[2] += cve*v0*v2;
        b6[3] += cve*v1*v1; b6[4] += cve*v1*v2; b6[5] += cve*v2*v2;
#pragma unroll
        for (int j = 0; j < 6; j++) atomicAdd(&blk6[nd4[k]*6 + j], b6[j]);
    }
    flag_bar(slots, 1);

    // ---- local inverses: elements (masked, per node) and owners ----
    float ib[4][6], nmask4[4];
#pragma unroll
    for (int k = 0; k < 4; k++) {
        float bm = boundary[nd4[k]] ? 0.f : 1.f;
        nmask4[k] = bm;
        float s6[6];
#pragma unroll
        for (int j = 0; j < 6; j++) s6[j] = blk6[nd4[k]*6 + j];
        float iv[6];
        sym_inv(s6, iv);
#pragma unroll
        for (int j = 0; j < 6; j++) ib[k][j] = iv[j] * bm;
    }

    const int own = blockIdx.x * 64 + threadIdx.x;   // exact: 32*64 = 2048
    const bool ownval = (threadIdx.x < 64);
    float iO[6] = {0,0,0,0,0,0};
    float maskO = 0.f;
    float xO[3]={0,0,0}, rO[3]={0,0,0}, uO[3]={0,0,0}, wO[3]={0,0,0}, mO[3]={0,0,0};
    float zO[3]={0,0,0}, qO[3]={0,0,0}, pO[3]={0,0,0}, sO[3]={0,0,0};
    if (ownval) {
        maskO = boundary[own] ? 0.f : 1.f;
        float s6[6];
#pragma unroll
        for (int j = 0; j < 6; j++) s6[j] = blk6[own*6 + j];
        float iv[6];
        sym_inv(s6, iv);
#pragma unroll
        for (int j = 0; j < 6; j++) iO[j] = iv[j] * maskO;
#pragma unroll
        for (int j = 0; j < 3; j++) rO[j] = bvec[3*own+j] * maskO;
        sym_apply(iO, rO, uO);
    }

    // ---- phase -1: scatter A*u0 into buf2 ----
    {
        float u0e[12];
#pragma unroll
        for (int k = 0; k < 4; k++) {
            float bb[3] = { bvec[3*nd4[k]], bvec[3*nd4[k]+1], bvec[3*nd4[k]+2] };
            sym_apply(ib[k], bb, &u0e[3*k]);
        }
        float y[12];
        matvec(u0e, y);
        float* v2 = val + 2 * 8192;
#pragma unroll
        for (int kk = 0; kk < 4; kk++)
#pragma unroll
            for (int c = 0; c < 3; c++) atomicAdd(&v2[4*nd4[kk]+c], y[3*kk+c]);
    }
    flag_bar(slots, 2);

    // ---- phase 0: consume buf2 (w0); init replicas/owner; scatter A*m0 -> buf0; dots(0) ----
    float w_e[12], z_e[12];
    {
        const float* vR = val + 2 * 8192;
#pragma unroll
        for (int kk = 0; kk < 4; kk++) {
            float4 t = *reinterpret_cast<const float4*>(&vR[4*nd4[kk]]);
            w_e[3*kk]   = t.x * nmask4[kk];
            w_e[3*kk+1] = t.y * nmask4[kk];
            w_e[3*kk+2] = t.z * nmask4[kk];
            z_e[3*kk] = 0.f; z_e[3*kk+1] = 0.f; z_e[3*kk+2] = 0.f;
        }
        float me[12];
#pragma unroll
        for (int kk = 0; kk < 4; kk++) sym_apply(ib[kk], &w_e[3*kk], &me[3*kk]);
        float y[12];
        matvec(me, y);
        float* vS = val;   // buf0
#pragma unroll
        for (int kk = 0; kk < 4; kk++)
#pragma unroll
            for (int c = 0; c < 3; c++) atomicAdd(&vS[4*nd4[kk]+c], y[3*kk+c]);

        if (ownval) {
            float gn = 0.f, dn = 0.f;
            float4 t = *reinterpret_cast<const float4*>(&vR[4*own]);
            wO[0] = t.x * maskO; wO[1] = t.y * maskO; wO[2] = t.z * maskO;
            sym_apply(iO, wO, mO);
#pragma unroll
            for (int j = 0; j < 3; j++) {
                gn += rO[j]*uO[j]; dn += wO[j]*uO[j];
            }
            bfly2(gn, dn);
            if (threadIdx.x == 0) {
                astf(&gdot[blockIdx.x], gn);
                astf(&gdot[64 + blockIdx.x], dn);
            }
        }
    }
    flag_bar(slots, 3);

    // ---- main loop: FIXED NPH iterations, one phase, one barrier each ----
    int rd = 0, sc = 1, ze = 2;
    float gp = 1.f, ap = 1.f;
    unsigned tgt = 4;

    for (int k = 1; k <= NPH; k++) {
        const float* vR = val + rd * 8192;

        // gather n early (overlaps dot completion)
        float ne[12];
#pragma unroll
        for (int kk = 0; kk < 4; kk++) {
            float4 t = *reinterpret_cast<const float4*>(&vR[4*nd4[kk]]);
            ne[3*kk]   = t.x * nmask4[kk];
            ne[3*kk+1] = t.y * nmask4[kk];
            ne[3*kk+2] = t.z * nmask4[kk];
        }
        float nO[3] = {0,0,0};
        if (ownval) {
            float4 t = *reinterpret_cast<const float4*>(&vR[4*own]);
            nO[0] = t.x * maskO; nO[1] = t.y * maskO; nO[2] = t.z * maskO;
        }

        // cross-block dot completion (wave 0; slots 32..63 are zero-padding)
        if (threadIdx.x < 64) {
            const float* dbase = gdot + ((k - 1) & 1) * 128;
            float g0 = aldf(&dbase[lane]);
            float d0 = aldf(&dbase[64 + lane]);
            bfly2(g0, d0);
            if (threadIdx.x == 0) { sd[0] = g0; sd[1] = d0; }
        }
        __syncthreads();
        float gam = sd[0], del = sd[1];

        float beta  = (k == 1) ? 0.f : ((gp != 0.f) ? gam / gp : 0.f);
        float den   = (k == 1) ? del : (del - beta * gam / ((ap != 0.f) ? ap : 1.f));
        float alpha = (den != 0.f) ? gam / den : 0.f;

        // element replica update + matvec + scatter into buffer sc
        {
#pragma unroll
            for (int t = 0; t < 12; t++) {
                z_e[t] = ne[t] + beta * z_e[t];
                w_e[t] -= alpha * z_e[t];
            }
            float me[12];
#pragma unroll
            for (int kk = 0; kk < 4; kk++) sym_apply(ib[kk], &w_e[3*kk], &me[3*kk]);
            float y[12];
            matvec(me, y);
            float* vS = val + sc * 8192;
#pragma unroll
            for (int kk = 0; kk < 4; kk++)
#pragma unroll
                for (int c = 0; c < 3; c++) atomicAdd(&vS[4*nd4[kk]+c], y[3*kk+c]);
        }

        // owner recurrences + dot publish + zero buffer ze
        if (ownval) {
            float gn = 0.f, dn = 0.f;
#pragma unroll
            for (int j = 0; j < 3; j++) {
                zO[j] = nO[j] + beta * zO[j];
                qO[j] = mO[j] + beta * qO[j];
                pO[j] = uO[j] + beta * pO[j];
                sO[j] = wO[j] + beta * sO[j];
                xO[j] += alpha * pO[j];
                rO[j] -= alpha * sO[j];
                uO[j] -= alpha * qO[j];
                wO[j] -= alpha * zO[j];
            }
            sym_apply(iO, wO, mO);
#pragma unroll
            for (int j = 0; j < 3; j++) {
                gn += rO[j]*uO[j]; dn += wO[j]*uO[j];
            }
            bfly2(gn, dn);
            float* gd_pub = gdot + (k & 1) * 128;
            if (threadIdx.x == 0) {
                astf(&gd_pub[blockIdx.x], gn);
                astf(&gd_pub[64 + blockIdx.x], dn);
            }
            float* vZ = val + ze * 8192;
            astf(&vZ[4*own+0], 0.f); astf(&vZ[4*own+1], 0.f);
            astf(&vZ[4*own+2], 0.f); astf(&vZ[4*own+3], 0.f);
        }

        gp = gam; ap = alpha;
        flag_bar(slots, tgt++);
        int t2 = rd; rd = sc; sc = ze; ze = t2;
    }

    if (ownval) {
#pragma unroll
        for (int j = 0; j < 3; j++) xout[3*own+j] = xO[j];
    }
}

extern "C" void kernel_launch(void* const* d_in, const int* in_sizes, int n_in,
                              void* d_out, int out_size, void* d_ws, size_t ws_size,
                              hipStream_t stream) {
    const float* theta = (const float*)d_in[0];
    const float* delta = (const float*)d_in[1];
    const float* ra    = (const float*)d_in[2];
    const float* rs    = (const float*)d_in[3];
    const float* rv    = (const float*)d_in[4];
    const float* vol   = (const float*)d_in[5];
    const float* b     = (const float*)d_in[6];
    const int* tets    = (const int*)d_in[7];
    const int* boundary = (const int*)d_in[8];
    float* x = (float*)d_out;
    float* ws = (float*)d_ws;

    hipMemsetAsync(ws, 0, WS_WORDS * sizeof(float), stream);
    pcg_kernel<<<dim3(NBLK), dim3(NTHR), 0, stream>>>(theta, delta, ra, rs, rv, vol, b,
                                                      tets, boundary, x, ws);
}

// Round 10
// 367.159 us; speedup vs baseline: 5.2508x; 5.2508x over previous
//
#include <hip/hip_runtime.h>

#define M_TETS 10240
#define N_NODES 2048
#define NPH 60
#define NBLK 32
#define NTHR 320
#define ADJCAP 64
#define SPIN_CAP 50000000

// ws float offsets
#define OFF_MBUF 12288             // blk6: 6*2048 at 0
#define OFF_YBUF 20480             // mbuf: 2048 x float4
#define OFF_GDOT 184320            // ybuf: 10240 x 4 x float4
#define OFF_CNT  184704            // gdot: 2 sets x 3 x 64
#define OFF_SLOT 186752            // cnt: 2048 u32
#define OFF_ADJ  186784            // slots: 32 u32
#define WS_ZERO  186784            // adj (2048*64 u32) needs no zeroing
#define WS_WORDS 317856

// log(500), log(10000)
__device__ __constant__ float LOG_A_MIN_C = 6.2146080984221914f;
__device__ __constant__ float LOG_A_MAX_C = 9.2103403719761836f;

__device__ __forceinline__ void rel_fence() { __builtin_amdgcn_fence(__ATOMIC_RELEASE, "agent"); }
__device__ __forceinline__ void acq_fence() { __builtin_amdgcn_fence(__ATOMIC_ACQUIRE, "agent"); }
__device__ __forceinline__ unsigned aldu(const unsigned* p) {
    return __hip_atomic_load(p, __ATOMIC_RELAXED, __HIP_MEMORY_SCOPE_AGENT);
}
__device__ __forceinline__ float aldf(const float* p) {
    return __hip_atomic_load(p, __ATOMIC_RELAXED, __HIP_MEMORY_SCOPE_AGENT);
}
__device__ __forceinline__ void astf(float* p, float v) {
    __hip_atomic_store(p, v, __ATOMIC_RELAXED, __HIP_MEMORY_SCOPE_AGENT);
}
__device__ __forceinline__ void astu(unsigned* p, unsigned v) {
    __hip_atomic_store(p, v, __ATOMIC_RELAXED, __HIP_MEMORY_SCOPE_AGENT);
}

// Distributed-flag barrier: one publish per block, 32-lane parallel poll.
__device__ __forceinline__ void flag_bar(unsigned* slots, unsigned tgt) {
    rel_fence();
    __syncthreads();
    if (threadIdx.x == 0) astu(&slots[blockIdx.x], tgt);
    if (threadIdx.x < NBLK) {
        int guard = 0;
        while (aldu(&slots[threadIdx.x]) < tgt && ++guard < SPIN_CAP) {}
    }
    __syncthreads();
    acq_fence();
}

__device__ __forceinline__ void bfly3(float& a, float& b, float& c) {
#pragma unroll
    for (int off = 32; off > 0; off >>= 1) {
        a += __shfl_xor(a, off);
        b += __shfl_xor(b, off);
        c += __shfl_xor(c, off);
    }
}

// symmetric 3x3 apply: s6 = [00,01,02,11,12,22]
__device__ __forceinline__ void sym_apply(const float* s6, const float* v, float* out) {
    out[0] = s6[0]*v[0] + s6[1]*v[1] + s6[2]*v[2];
    out[1] = s6[1]*v[0] + s6[3]*v[1] + s6[4]*v[2];
    out[2] = s6[2]*v[0] + s6[4]*v[1] + s6[5]*v[2];
}

__device__ __forceinline__ void sym_inv(const float* s, float* o) {
    float a = s[0], b = s[1], c = s[2], d = s[3], e = s[4], f = s[5];
    float C00 = d*f - e*e, C01 = c*e - b*f, C02 = b*e - c*d;
    float id = 1.0f / (a*C00 + b*C01 + c*C02);
    o[0] = C00*id; o[1] = C01*id; o[2] = C02*id;
    o[3] = (a*f - c*c)*id; o[4] = (b*c - a*e)*id; o[5] = (a*d - b*b)*id;
}

__global__ void __launch_bounds__(NTHR, 1) pcg_kernel(
    const float* __restrict__ theta, const float* __restrict__ delta,
    const float* __restrict__ ra, const float* __restrict__ rs, const float* __restrict__ rv,
    const float* __restrict__ vol, const float* __restrict__ bvec,
    const int* __restrict__ tets, const int* __restrict__ boundary,
    float* __restrict__ xout, float* __restrict__ ws)
{
    const int tid = blockIdx.x * NTHR + threadIdx.x;   // element id, 10240 total
    const int lane = threadIdx.x & 63;
    __shared__ float sd[1];

    float*    blk6  = ws;
    float*    mbuf  = ws + OFF_MBUF;
    float*    ybuf  = ws + OFF_YBUF;
    float*    gdot  = ws + OFF_GDOT;
    unsigned* cnt   = (unsigned*)(ws + OFF_CNT);
    unsigned* slots = (unsigned*)(ws + OFF_SLOT);
    unsigned* adj   = (unsigned*)(ws + OFF_ADJ);

    // ---- element data -> registers (ws head pre-zeroed by hipMemsetAsync) ----
    float A[3][12], S[3][12], V[12];
    int nd4[4];
    float cae, cse, cve;
    {
        const int e = tid;
#pragma unroll
        for (int a = 0; a < 3; a++)
#pragma unroll
            for (int i = 0; i < 12; i++) {
                A[a][i] = ra[e * 36 + a * 12 + i];
                S[a][i] = rs[e * 36 + a * 12 + i];
            }
#pragma unroll
        for (int i = 0; i < 12; i++) V[i] = rv[e * 12 + i];
        const int4 t = reinterpret_cast<const int4*>(tets)[e];
        nd4[0] = t.x; nd4[1] = t.y; nd4[2] = t.z; nd4[3] = t.w;
        float la = theta[0] + delta[e];
        la = fminf(fmaxf(la, LOG_A_MIN_C), LOG_A_MAX_C);
        float al = expf(la);
        float v = vol[e];
        cae = v * al; cse = 2.0f * v * al; cve = 8.0f * v * al;
    }

    auto matvec = [&](const float* pe, float* y) {
#pragma unroll
        for (int t = 0; t < 12; t++) y[t] = 0.f;
#pragma unroll
        for (int a = 0; a < 3; a++) {
            float qa = 0.f, qs = 0.f;
#pragma unroll
            for (int t = 0; t < 12; t++) { qa += A[a][t] * pe[t]; qs += S[a][t] * pe[t]; }
            qa *= cae; qs *= cse;
#pragma unroll
            for (int t = 0; t < 12; t++) y[t] += qa * A[a][t] + qs * S[a][t];
        }
        float qv = 0.f;
#pragma unroll
        for (int t = 0; t < 12; t++) qv += V[t] * pe[t];
        qv *= cve;
#pragma unroll
        for (int t = 0; t < 12; t++) y[t] += qv * V[t];
    };

    // ---- S1: per-node 3x3 blocks of K (atomics, one-time) + adjacency build ----
#pragma unroll
    for (int k = 0; k < 4; k++) {
        float b6[6] = {0,0,0,0,0,0};
#pragma unroll
        for (int a = 0; a < 3; a++) {
            float x0 = A[a][3*k], x1 = A[a][3*k+1], x2 = A[a][3*k+2];
            float s0 = S[a][3*k], s1 = S[a][3*k+1], s2 = S[a][3*k+2];
            b6[0] += cae*x0*x0 + cse*s0*s0;
            b6[1] += cae*x0*x1 + cse*s0*s1;
            b6[2] += cae*x0*x2 + cse*s0*s2;
            b6[3] += cae*x1*x1 + cse*s1*s1;
            b6[4] += cae*x1*x2 + cse*s1*s2;
            b6[5] += cae*x2*x2 + cse*s2*s2;
        }
        float v0 = V[3*k], v1 = V[3*k+1], v2 = V[3*k+2];
        b6[0] += cve*v0*v0; b6[1] += cve*v0*v1; b6[2] += cve*v0*v2;
        b6[3] += cve*v1*v1; b6[4] += cve*v1*v2; b6[5] += cve*v2*v2;
#pragma unroll
        for (int j = 0; j < 6; j++) atomicAdd(&blk6[nd4[k]*6 + j], b6[j]);
        unsigned pos = atomicAdd(&cnt[nd4[k]], 1u);
        if (pos < ADJCAP) adj[nd4[k] * ADJCAP + pos] = (unsigned)(tid * 4 + k);
    }
    flag_bar(slots, 1);

    // ---- owners: invert 3x3, r0/u0, publish mbuf = u0 ----
    const int own = blockIdx.x * 64 + threadIdx.x;   // exact: 32*64 = 2048
    const bool ownval = (threadIdx.x < 64);
    float iO[6] = {0,0,0,0,0,0};
    float maskO = 0.f;
    unsigned degO = 0;
    float xO[3]={0,0,0}, rO[3]={0,0,0}, uO[3]={0,0,0}, wO[3]={0,0,0}, mO[3]={0,0,0};
    float zO[3]={0,0,0}, qO[3]={0,0,0}, pO[3]={0,0,0}, sO[3]={0,0,0};
    if (ownval) {
        maskO = boundary[own] ? 0.f : 1.f;
        unsigned c = cnt[own];
        degO = c < ADJCAP ? c : ADJCAP;
        float s6[6];
#pragma unroll
        for (int j = 0; j < 6; j++) s6[j] = blk6[own*6 + j];
        float iv[6];
        sym_inv(s6, iv);
#pragma unroll
        for (int j = 0; j < 6; j++) iO[j] = iv[j] * maskO;
#pragma unroll
        for (int j = 0; j < 3; j++) rO[j] = bvec[3*own+j] * maskO;
        sym_apply(iO, rO, uO);
        *reinterpret_cast<float4*>(&mbuf[own*4]) = make_float4(uO[0], uO[1], uO[2], 0.f);
    }
    flag_bar(slots, 2);

    // ---- main loop: A-phase (elements: y = K*m) / B-phase (owners: gather + CG) ----
    unsigned tgt = 3;
    float gp = 1.f, ap = 1.f, stopv = 0.f;

    for (int k = 0; k <= NPH; k++) {
        // ===== A-phase: elements =====
        {
            float pe[12];
#pragma unroll
            for (int kk = 0; kk < 4; kk++) {
                float4 mm = *reinterpret_cast<const float4*>(&mbuf[nd4[kk]*4]);
                pe[3*kk] = mm.x; pe[3*kk+1] = mm.y; pe[3*kk+2] = mm.z;
            }
            float y[12];
            matvec(pe, y);
            float4* yb = reinterpret_cast<float4*>(&ybuf[tid * 16]);
            yb[0] = make_float4(y[0], y[1],  y[2],  0.f);
            yb[1] = make_float4(y[3], y[4],  y[5],  0.f);
            yb[2] = make_float4(y[6], y[7],  y[8],  0.f);
            yb[3] = make_float4(y[9], y[10], y[11], 0.f);
        }
        flag_bar(slots, tgt++);

        // ===== B-phase: owners =====
        if (ownval) {
            float gam = 0.f, del = 0.f, rho = 0.f, beta = 0.f, alpha = 0.f;
            if (k >= 1) {
                const float* db = gdot + ((k - 1) & 1) * 192;
                float g = aldf(&db[lane]);
                float d = aldf(&db[64 + lane]);
                float q = aldf(&db[128 + lane]);
                bfly3(g, d, q);
                gam = g; del = d; rho = q;
                if (lane == 0) sd[0] = rho;
                beta = (k == 1) ? 0.f : ((gp != 0.f) ? gam / gp : 0.f);
                float den = (k == 1) ? del : (del - beta * gam / ((ap != 0.f) ? ap : 1.f));
                alpha = (den != 0.f) ? gam / den : 0.f;
            }
            // gather n = sum of adjacent element contributions (no atomics)
            float n0 = 0.f, n1 = 0.f, n2 = 0.f;
            for (unsigned j = 0; j < degO; j++) {
                unsigned enc = adj[own * ADJCAP + j];
                float4 yv = *reinterpret_cast<const float4*>(&ybuf[enc * 4]);
                n0 += yv.x; n1 += yv.y; n2 += yv.z;
            }
            n0 *= maskO; n1 *= maskO; n2 *= maskO;

            if (k == 0) {
                wO[0] = n0; wO[1] = n1; wO[2] = n2;        // w0 = A u0 (masked)
            } else {
                float nn[3] = {n0, n1, n2};
#pragma unroll
                for (int j = 0; j < 3; j++) {
                    zO[j] = nn[j] + beta * zO[j];
                    qO[j] = mO[j] + beta * qO[j];
                    pO[j] = uO[j] + beta * pO[j];
                    sO[j] = wO[j] + beta * sO[j];
                    xO[j] += alpha * pO[j];
                    rO[j] -= alpha * sO[j];
                    uO[j] -= alpha * qO[j];
                    wO[j] -= alpha * zO[j];
                }
                gp = gam; ap = alpha;
            }
            sym_apply(iO, wO, mO);
            *reinterpret_cast<float4*>(&mbuf[own*4]) = make_float4(mO[0], mO[1], mO[2], 0.f);

            float gn = 0.f, dn = 0.f, qn = 0.f;
#pragma unroll
            for (int j = 0; j < 3; j++) {
                gn += rO[j]*uO[j]; dn += wO[j]*uO[j]; qn += rO[j]*rO[j];
            }
            bfly3(gn, dn, qn);
            if (lane == 0) {
                float* gpub = gdot + (k & 1) * 192;
                astf(&gpub[blockIdx.x], gn);
                astf(&gpub[64 + blockIdx.x], dn);
                astf(&gpub[128 + blockIdx.x], qn);
            }
        }
        flag_bar(slots, tgt++);

        // uniform stop decision (sd written at B(k), k>=1; same value in every block)
        if (k >= 1) {
            float rr = sd[0];
            if (k == 1) stopv = rr * 1e-8f;        // rel residual 1e-4
            else if (rr <= stopv) break;
        }
    }

    if (ownval) {
#pragma unroll
        for (int j = 0; j < 3; j++) xout[3*own+j] = xO[j];
    }
}

extern "C" void kernel_launch(void* const* d_in, const int* in_sizes, int n_in,
                              void* d_out, int out_size, void* d_ws, size_t ws_size,
                              hipStream_t stream) {
    const float* theta = (const float*)d_in[0];
    const float* delta = (const float*)d_in[1];
    const float* ra    = (const float*)d_in[2];
    const float* rs    = (const float*)d_in[3];
    const float* rv    = (const float*)d_in[4];
    const float* vol   = (const float*)d_in[5];
    const float* b     = (const float*)d_in[6];
    const int* tets    = (const int*)d_in[7];
    const int* boundary = (const int*)d_in[8];
    float* x = (float*)d_out;
    float* ws = (float*)d_ws;

    hipMemsetAsync(ws, 0, WS_ZERO * sizeof(float), stream);
    pcg_kernel<<<dim3(NBLK), dim3(NTHR), 0, stream>>>(theta, delta, ra, rs, rv, vol, b,
                                                      tets, boundary, x, ws);
}

// Round 11
// 334.505 us; speedup vs baseline: 5.7634x; 1.0976x over previous
//
#include <hip/hip_runtime.h>

#define M_TETS 10240
#define N_NODES 2048
#define NPH 60
#define NBLK 32
#define NTHR 320
#define ADJCAP 64
#define SPIN_CAP 50000000

// ws float offsets
#define OFF_MBUF 12288             // blk6: 6*2048 at 0
#define OFF_YBUF 20480             // mbuf: 2048 x float4
#define OFF_GDOT 184320            // ybuf: 10240 x 4 x float4
#define OFF_CNT  184704            // gdot: 2 sets x 3 x 64
#define OFF_SLOT 186752            // cnt: 2048 u32
#define OFF_ADJ  186784            // slots: 32 u32
#define WS_ZERO  186784            // adj (2048*64 u32) needs no zeroing
#define WS_WORDS 317856

// log(500), log(10000)
__device__ __constant__ float LOG_A_MIN_C = 6.2146080984221914f;
__device__ __constant__ float LOG_A_MAX_C = 9.2103403719761836f;

__device__ __forceinline__ void rel_fence() { __builtin_amdgcn_fence(__ATOMIC_RELEASE, "agent"); }
__device__ __forceinline__ void acq_fence() { __builtin_amdgcn_fence(__ATOMIC_ACQUIRE, "agent"); }
__device__ __forceinline__ unsigned aldu(const unsigned* p) {
    return __hip_atomic_load(p, __ATOMIC_RELAXED, __HIP_MEMORY_SCOPE_AGENT);
}
__device__ __forceinline__ float aldf(const float* p) {
    return __hip_atomic_load(p, __ATOMIC_RELAXED, __HIP_MEMORY_SCOPE_AGENT);
}
__device__ __forceinline__ void astf(float* p, float v) {
    __hip_atomic_store(p, v, __ATOMIC_RELAXED, __HIP_MEMORY_SCOPE_AGENT);
}
__device__ __forceinline__ void astu(unsigned* p, unsigned v) {
    __hip_atomic_store(p, v, __ATOMIC_RELAXED, __HIP_MEMORY_SCOPE_AGENT);
}

// Flag barrier. FULL=true: full release/acquire fences (setup phases; flushes
// plain-store data: adj lists, memset lines, blk6). FULL=false: fence-free —
// correct because ALL in-loop shared data moves via agent-scope atomics, which
// are coherent at the LLC without wbl2/inv; release = drain own stores
// (s_waitcnt vmcnt(0)), acquire = in-order issue after the poll's branch.
template<bool FULL>
__device__ __forceinline__ void flag_bar(unsigned* slots, unsigned tgt) {
    if (FULL) rel_fence();
    else asm volatile("s_waitcnt vmcnt(0)" ::: "memory");
    __syncthreads();
    if (threadIdx.x == 0) astu(&slots[blockIdx.x], tgt);
    if (threadIdx.x < NBLK) {
        int guard = 0;
        while (aldu(&slots[threadIdx.x]) < tgt && ++guard < SPIN_CAP) {}
    }
    __syncthreads();
    if (FULL) acq_fence();
    else asm volatile("" ::: "memory");
}

__device__ __forceinline__ void bfly3(float& a, float& b, float& c) {
#pragma unroll
    for (int off = 32; off > 0; off >>= 1) {
        a += __shfl_xor(a, off);
        b += __shfl_xor(b, off);
        c += __shfl_xor(c, off);
    }
}

// symmetric 3x3 apply: s6 = [00,01,02,11,12,22]
__device__ __forceinline__ void sym_apply(const float* s6, const float* v, float* out) {
    out[0] = s6[0]*v[0] + s6[1]*v[1] + s6[2]*v[2];
    out[1] = s6[1]*v[0] + s6[3]*v[1] + s6[4]*v[2];
    out[2] = s6[2]*v[0] + s6[4]*v[1] + s6[5]*v[2];
}

__device__ __forceinline__ void sym_inv(const float* s, float* o) {
    float a = s[0], b = s[1], c = s[2], d = s[3], e = s[4], f = s[5];
    float C00 = d*f - e*e, C01 = c*e - b*f, C02 = b*e - c*d;
    float id = 1.0f / (a*C00 + b*C01 + c*C02);
    o[0] = C00*id; o[1] = C01*id; o[2] = C02*id;
    o[3] = (a*f - c*c)*id; o[4] = (b*c - a*e)*id; o[5] = (a*d - b*b)*id;
}

__global__ void __launch_bounds__(NTHR, 1) pcg_kernel(
    const float* __restrict__ theta, const float* __restrict__ delta,
    const float* __restrict__ ra, const float* __restrict__ rs, const float* __restrict__ rv,
    const float* __restrict__ vol, const float* __restrict__ bvec,
    const int* __restrict__ tets, const int* __restrict__ boundary,
    float* __restrict__ xout, float* __restrict__ ws)
{
    const int tid = blockIdx.x * NTHR + threadIdx.x;   // element id, 10240 total
    const int lane = threadIdx.x & 63;
    __shared__ float sd[1];

    float*    blk6  = ws;
    float*    mbuf  = ws + OFF_MBUF;
    float*    ybuf  = ws + OFF_YBUF;
    float*    gdot  = ws + OFF_GDOT;
    unsigned* cnt   = (unsigned*)(ws + OFF_CNT);
    unsigned* slots = (unsigned*)(ws + OFF_SLOT);
    unsigned* adj   = (unsigned*)(ws + OFF_ADJ);

    // ---- element data -> registers (ws head pre-zeroed by hipMemsetAsync) ----
    float A[3][12], S[3][12], V[12];
    int nd4[4];
    float cae, cse, cve;
    {
        const int e = tid;
#pragma unroll
        for (int a = 0; a < 3; a++)
#pragma unroll
            for (int i = 0; i < 12; i++) {
                A[a][i] = ra[e * 36 + a * 12 + i];
                S[a][i] = rs[e * 36 + a * 12 + i];
            }
#pragma unroll
        for (int i = 0; i < 12; i++) V[i] = rv[e * 12 + i];
        const int4 t = reinterpret_cast<const int4*>(tets)[e];
        nd4[0] = t.x; nd4[1] = t.y; nd4[2] = t.z; nd4[3] = t.w;
        float la = theta[0] + delta[e];
        la = fminf(fmaxf(la, LOG_A_MIN_C), LOG_A_MAX_C);
        float al = expf(la);
        float v = vol[e];
        cae = v * al; cse = 2.0f * v * al; cve = 8.0f * v * al;
    }

    auto matvec = [&](const float* pe, float* y) {
#pragma unroll
        for (int t = 0; t < 12; t++) y[t] = 0.f;
#pragma unroll
        for (int a = 0; a < 3; a++) {
            float qa = 0.f, qs = 0.f;
#pragma unroll
            for (int t = 0; t < 12; t++) { qa += A[a][t] * pe[t]; qs += S[a][t] * pe[t]; }
            qa *= cae; qs *= cse;
#pragma unroll
            for (int t = 0; t < 12; t++) y[t] += qa * A[a][t] + qs * S[a][t];
        }
        float qv = 0.f;
#pragma unroll
        for (int t = 0; t < 12; t++) qv += V[t] * pe[t];
        qv *= cve;
#pragma unroll
        for (int t = 0; t < 12; t++) y[t] += qv * V[t];
    };

    // ---- S1: per-node 3x3 blocks of K (one-time atomics) + adjacency build ----
#pragma unroll
    for (int k = 0; k < 4; k++) {
        float b6[6] = {0,0,0,0,0,0};
#pragma unroll
        for (int a = 0; a < 3; a++) {
            float x0 = A[a][3*k], x1 = A[a][3*k+1], x2 = A[a][3*k+2];
            float s0 = S[a][3*k], s1 = S[a][3*k+1], s2 = S[a][3*k+2];
            b6[0] += cae*x0*x0 + cse*s0*s0;
            b6[1] += cae*x0*x1 + cse*s0*s1;
            b6[2] += cae*x0*x2 + cse*s0*s2;
            b6[3] += cae*x1*x1 + cse*s1*s1;
            b6[4] += cae*x1*x2 + cse*s1*s2;
            b6[5] += cae*x2*x2 + cse*s2*s2;
        }
        float v0 = V[3*k], v1 = V[3*k+1], v2 = V[3*k+2];
        b6[0] += cve*v0*v0; b6[1] += cve*v0*v1; b6[2] += cve*v0*v2;
        b6[3] += cve*v1*v1; b6[4] += cve*v1*v2; b6[5] += cve*v2*v2;
#pragma unroll
        for (int j = 0; j < 6; j++) atomicAdd(&blk6[nd4[k]*6 + j], b6[j]);
        unsigned pos = atomicAdd(&cnt[nd4[k]], 1u);
        if (pos < ADJCAP) adj[nd4[k] * ADJCAP + pos] = (unsigned)(tid * 4 + k);
    }
    flag_bar<true>(slots, 1);    // full fences: flush adj plain stores, drop stale lines

    // ---- owners: invert 3x3, r0/u0, publish mbuf = u0 ----
    const int own = blockIdx.x * 64 + threadIdx.x;   // exact: 32*64 = 2048
    const bool ownval = (threadIdx.x < 64);
    float iO[6] = {0,0,0,0,0,0};
    float maskO = 0.f;
    unsigned degO = 0;
    float xO[3]={0,0,0}, rO[3]={0,0,0}, uO[3]={0,0,0}, wO[3]={0,0,0}, mO[3]={0,0,0};
    float zO[3]={0,0,0}, qO[3]={0,0,0}, pO[3]={0,0,0}, sO[3]={0,0,0};
    if (ownval) {
        maskO = boundary[own] ? 0.f : 1.f;
        unsigned c = aldu(&cnt[own]);
        degO = c < ADJCAP ? c : ADJCAP;
        float s6[6];
#pragma unroll
        for (int j = 0; j < 6; j++) s6[j] = blk6[own*6 + j];
        float iv[6];
        sym_inv(s6, iv);
#pragma unroll
        for (int j = 0; j < 6; j++) iO[j] = iv[j] * maskO;
#pragma unroll
        for (int j = 0; j < 3; j++) rO[j] = bvec[3*own+j] * maskO;
        sym_apply(iO, rO, uO);
#pragma unroll
        for (int j = 0; j < 3; j++) astf(&mbuf[own*4+j], uO[j]);
    }

    // element-side: masked B^-1 per node (plain loads OK after full-fence barrier)
    float ib[4][6], nmask4[4];
#pragma unroll
    for (int k = 0; k < 4; k++) {
        float bm = boundary[nd4[k]] ? 0.f : 1.f;
        nmask4[k] = bm;
        (void)bm;
    }
    flag_bar<true>(slots, 2);    // full fences: blk6/mbuf visible everywhere

    // ---- main loop: A-phase (elements: y = K*m) / B-phase (owners: gather + CG) ----
    unsigned tgt = 3;
    float gp = 1.f, ap = 1.f, stopv = 0.f;

    for (int k = 0; k <= NPH; k++) {
        // ===== A-phase: elements (all atomic loads/stores -> LLC) =====
        {
            float pe[12];
#pragma unroll
            for (int kk = 0; kk < 4; kk++) {
                pe[3*kk]   = aldf(&mbuf[nd4[kk]*4 + 0]);
                pe[3*kk+1] = aldf(&mbuf[nd4[kk]*4 + 1]);
                pe[3*kk+2] = aldf(&mbuf[nd4[kk]*4 + 2]);
            }
            float y[12];
            matvec(pe, y);
#pragma unroll
            for (int kk = 0; kk < 4; kk++) {
                astf(&ybuf[(tid*4+kk)*4 + 0], y[3*kk]);
                astf(&ybuf[(tid*4+kk)*4 + 1], y[3*kk+1]);
                astf(&ybuf[(tid*4+kk)*4 + 2], y[3*kk+2]);
            }
        }
        flag_bar<false>(slots, tgt++);

        // ===== B-phase: owners =====
        if (ownval) {
            float gam = 0.f, del = 0.f, rho = 0.f, beta = 0.f, alpha = 0.f;
            if (k >= 1) {
                const float* db = gdot + ((k - 1) & 1) * 192;
                float g = aldf(&db[lane]);
                float d = aldf(&db[64 + lane]);
                float q = aldf(&db[128 + lane]);
                bfly3(g, d, q);
                gam = g; del = d; rho = q;
                if (lane == 0) sd[0] = rho;
                beta = (k == 1) ? 0.f : ((gp != 0.f) ? gam / gp : 0.f);
                float den = (k == 1) ? del : (del - beta * gam / ((ap != 0.f) ? ap : 1.f));
                alpha = (den != 0.f) ? gam / den : 0.f;
            }
            // gather n = sum of adjacent element contributions (no RMW)
            float n0 = 0.f, n1 = 0.f, n2 = 0.f;
            for (unsigned j = 0; j < degO; j++) {
                unsigned enc = adj[own * ADJCAP + j];   // read-only, L1-cached
                n0 += aldf(&ybuf[enc * 4 + 0]);
                n1 += aldf(&ybuf[enc * 4 + 1]);
                n2 += aldf(&ybuf[enc * 4 + 2]);
            }
            n0 *= maskO; n1 *= maskO; n2 *= maskO;

            if (k == 0) {
                wO[0] = n0; wO[1] = n1; wO[2] = n2;        // w0 = A u0 (masked)
            } else {
                float nn[3] = {n0, n1, n2};
#pragma unroll
                for (int j = 0; j < 3; j++) {
                    zO[j] = nn[j] + beta * zO[j];
                    qO[j] = mO[j] + beta * qO[j];
                    pO[j] = uO[j] + beta * pO[j];
                    sO[j] = wO[j] + beta * sO[j];
                    xO[j] += alpha * pO[j];
                    rO[j] -= alpha * sO[j];
                    uO[j] -= alpha * qO[j];
                    wO[j] -= alpha * zO[j];
                }
                gp = gam; ap = alpha;
            }
            sym_apply(iO, wO, mO);
#pragma unroll
            for (int j = 0; j < 3; j++) astf(&mbuf[own*4+j], mO[j]);

            float gn = 0.f, dn = 0.f, qn = 0.f;
#pragma unroll
            for (int j = 0; j < 3; j++) {
                gn += rO[j]*uO[j]; dn += wO[j]*uO[j]; qn += rO[j]*rO[j];
            }
            bfly3(gn, dn, qn);
            if (lane == 0) {
                float* gpub = gdot + (k & 1) * 192;
                astf(&gpub[blockIdx.x], gn);
                astf(&gpub[64 + blockIdx.x], dn);
                astf(&gpub[128 + blockIdx.x], qn);
            }
        }
        flag_bar<false>(slots, tgt++);

        // uniform stop decision (sd written in B(k), k>=1; identical in every block)
        if (k >= 1) {
            float rr = sd[0];
            if (k == 1) stopv = rr * 1e-8f;        // rel residual 1e-4
            else if (rr <= stopv) break;
        }
    }

    if (ownval) {
#pragma unroll
        for (int j = 0; j < 3; j++) xout[3*own+j] = xO[j];
    }
}

extern "C" void kernel_launch(void* const* d_in, const int* in_sizes, int n_in,
                              void* d_out, int out_size, void* d_ws, size_t ws_size,
                              hipStream_t stream) {
    const float* theta = (const float*)d_in[0];
    const float* delta = (const float*)d_in[1];
    const float* ra    = (const float*)d_in[2];
    const float* rs    = (const float*)d_in[3];
    const float* rv    = (const float*)d_in[4];
    const float* vol   = (const float*)d_in[5];
    const float* b     = (const float*)d_in[6];
    const int* tets    = (const int*)d_in[7];
    const int* boundary = (const int*)d_in[8];
    float* x = (float*)d_out;
    float* ws = (float*)d_ws;

    hipMemsetAsync(ws, 0, WS_ZERO * sizeof(float), stream);
    pcg_kernel<<<dim3(NBLK), dim3(NTHR), 0, stream>>>(theta, delta, ra, rs, rv, vol, b,
                                                      tets, boundary, x, ws);
}

// Round 12
// 328.578 us; speedup vs baseline: 5.8674x; 1.0180x over previous
//
#include <hip/hip_runtime.h>

#define M_TETS 10240
#define N_NODES 2048
#define NPH 60
#define NBLK 16
#define NTHR 640
#define NOWN 128           // owned nodes per block = 2048/16
#define SPIN_CAP 50000000

typedef float f32x4 __attribute__((ext_vector_type(4)));

// ws float offsets
#define OFF_SLOT 12288     // blk6: 6*2048 at 0
#define OFF_GDOT 12304     // slots: 16
#define OFF_MBUF 12400     // gdot: 2 sets x 3 comps x 16
#define OFF_PBUF 20592     // mbuf: 2048 x 4
#define WS_ZERO  12304     // memset blk6 + slots only

// log(500), log(10000)
__device__ __constant__ float LOG_A_MIN_C = 6.2146080984221914f;
__device__ __constant__ float LOG_A_MAX_C = 9.2103403719761836f;

__device__ __forceinline__ void rel_fence() { __builtin_amdgcn_fence(__ATOMIC_RELEASE, "agent"); }
__device__ __forceinline__ void acq_fence() { __builtin_amdgcn_fence(__ATOMIC_ACQUIRE, "agent"); }
__device__ __forceinline__ unsigned aldu(const unsigned* p) {
    return __hip_atomic_load(p, __ATOMIC_RELAXED, __HIP_MEMORY_SCOPE_AGENT);
}
__device__ __forceinline__ float aldf(const float* p) {
    return __hip_atomic_load(p, __ATOMIC_RELAXED, __HIP_MEMORY_SCOPE_AGENT);
}
__device__ __forceinline__ void astf(float* p, float v) {
    __hip_atomic_store(p, v, __ATOMIC_RELAXED, __HIP_MEMORY_SCOPE_AGENT);
}
__device__ __forceinline__ void astu(unsigned* p, unsigned v) {
    __hip_atomic_store(p, v, __ATOMIC_RELAXED, __HIP_MEMORY_SCOPE_AGENT);
}

// coherent 16B load/store: volatile vector access -> global_load/store_dwordx4 sc0 sc1
__device__ __forceinline__ f32x4 vload4(const float* p) {
    return *(volatile const f32x4*)p;
}
__device__ __forceinline__ void vstore4(float* p, f32x4 v) {
    *(volatile f32x4*)p = v;
}

// Flag barrier. FULL=true: full fences (setup; flushes plain-store data).
// FULL=false: fence-free — all in-loop shared data moves via coherent (sc0/sc1)
// or atomic ops; release = s_waitcnt vmcnt(0), acquire = in-order issue.
template<bool FULL>
__device__ __forceinline__ void flag_bar(unsigned* slots, unsigned tgt) {
    if (FULL) rel_fence();
    else asm volatile("s_waitcnt vmcnt(0)" ::: "memory");
    __syncthreads();
    if (threadIdx.x == 0) astu(&slots[blockIdx.x], tgt);
    if (threadIdx.x < NBLK) {
        int guard = 0;
        while (aldu(&slots[threadIdx.x]) < tgt && ++guard < SPIN_CAP) {}
    }
    __syncthreads();
    if (FULL) acq_fence();
    else asm volatile("" ::: "memory");
}

__device__ __forceinline__ void bfly3w(float& a, float& b, float& c, int maxoff) {
    for (int off = maxoff; off > 0; off >>= 1) {
        a += __shfl_xor(a, off);
        b += __shfl_xor(b, off);
        c += __shfl_xor(c, off);
    }
}

// symmetric 3x3 apply: s6 = [00,01,02,11,12,22]
__device__ __forceinline__ void sym_apply(const float* s6, const float* v, float* out) {
    out[0] = s6[0]*v[0] + s6[1]*v[1] + s6[2]*v[2];
    out[1] = s6[1]*v[0] + s6[3]*v[1] + s6[4]*v[2];
    out[2] = s6[2]*v[0] + s6[4]*v[1] + s6[5]*v[2];
}

__device__ __forceinline__ void sym_inv(const float* s, float* o) {
    float a = s[0], b = s[1], c = s[2], d = s[3], e = s[4], f = s[5];
    float C00 = d*f - e*e, C01 = c*e - b*f, C02 = b*e - c*d;
    float id = 1.0f / (a*C00 + b*C01 + c*C02);
    o[0] = C00*id; o[1] = C01*id; o[2] = C02*id;
    o[3] = (a*f - c*c)*id; o[4] = (b*c - a*e)*id; o[5] = (a*d - b*b)*id;
}

__global__ void __launch_bounds__(NTHR, 1) pcg_kernel(
    const float* __restrict__ theta, const float* __restrict__ delta,
    const float* __restrict__ ra, const float* __restrict__ rs, const float* __restrict__ rv,
    const float* __restrict__ vol, const float* __restrict__ bvec,
    const int* __restrict__ tets, const int* __restrict__ boundary,
    float* __restrict__ xout, float* __restrict__ ws)
{
    const int tid = blockIdx.x * NTHR + threadIdx.x;   // element id, 10240 total
    const int lane = threadIdx.x & 63;
    const int wv = threadIdx.x >> 6;

    __shared__ f32x4 mstage[N_NODES];       // 32 KB
    __shared__ float nacc[3 * N_NODES];     // 24 KB
    __shared__ float sred[2][4];
    __shared__ float sd[4];

    float*    blk6  = ws;
    unsigned* slots = (unsigned*)(ws + OFF_SLOT);
    float*    gdot  = ws + OFF_GDOT;
    float*    mbuf  = ws + OFF_MBUF;
    float*    pbuf  = ws + OFF_PBUF;

    // ---- element data -> registers ----
    float A[3][12], S[3][12], V[12];
    int nd4[4];
    float cae, cse, cve;
    {
        const int e = tid;
#pragma unroll
        for (int a = 0; a < 3; a++)
#pragma unroll
            for (int i = 0; i < 12; i++) {
                A[a][i] = ra[e * 36 + a * 12 + i];
                S[a][i] = rs[e * 36 + a * 12 + i];
            }
#pragma unroll
        for (int i = 0; i < 12; i++) V[i] = rv[e * 12 + i];
        const int4 t = reinterpret_cast<const int4*>(tets)[e];
        nd4[0] = t.x; nd4[1] = t.y; nd4[2] = t.z; nd4[3] = t.w;
        float la = theta[0] + delta[e];
        la = fminf(fmaxf(la, LOG_A_MIN_C), LOG_A_MAX_C);
        float al = expf(la);
        float v = vol[e];
        cae = v * al; cse = 2.0f * v * al; cve = 8.0f * v * al;
    }

    auto matvec = [&](const float* pe, float* y) {
#pragma unroll
        for (int t = 0; t < 12; t++) y[t] = 0.f;
#pragma unroll
        for (int a = 0; a < 3; a++) {
            float qa = 0.f, qs = 0.f;
#pragma unroll
            for (int t = 0; t < 12; t++) { qa += A[a][t] * pe[t]; qs += S[a][t] * pe[t]; }
            qa *= cae; qs *= cse;
#pragma unroll
            for (int t = 0; t < 12; t++) y[t] += qa * A[a][t] + qs * S[a][t];
        }
        float qv = 0.f;
#pragma unroll
        for (int t = 0; t < 12; t++) qv += V[t] * pe[t];
        qv *= cve;
#pragma unroll
        for (int t = 0; t < 12; t++) y[t] += qv * V[t];
    };

    // ---- S1: per-node 3x3 blocks of K (one-time global atomics, ws pre-zeroed) ----
#pragma unroll
    for (int k = 0; k < 4; k++) {
        float b6[6] = {0,0,0,0,0,0};
#pragma unroll
        for (int a = 0; a < 3; a++) {
            float x0 = A[a][3*k], x1 = A[a][3*k+1], x2 = A[a][3*k+2];
            float s0 = S[a][3*k], s1 = S[a][3*k+1], s2 = S[a][3*k+2];
            b6[0] += cae*x0*x0 + cse*s0*s0;
            b6[1] += cae*x0*x1 + cse*s0*s1;
            b6[2] += cae*x0*x2 + cse*s0*s2;
            b6[3] += cae*x1*x1 + cse*s1*s1;
            b6[4] += cae*x1*x2 + cse*s1*s2;
            b6[5] += cae*x2*x2 + cse*s2*s2;
        }
        float v0 = V[3*k], v1 = V[3*k+1], v2 = V[3*k+2];
        b6[0] += cve*v0*v0; b6[1] += cve*v0*v1; b6[2] += cve*v0*v2;
        b6[3] += cve*v1*v1; b6[4] += cve*v1*v2; b6[5] += cve*v2*v2;
#pragma unroll
        for (int j = 0; j < 6; j++) atomicAdd(&blk6[nd4[k]*6 + j], b6[j]);
    }
    flag_bar<true>(slots, 1);

    // ---- owners: invert masked 3x3, r0/u0, publish mbuf = u0 ----
    const int own = blockIdx.x * NOWN + threadIdx.x;
    const bool ownval = (threadIdx.x < NOWN);
    float iO[6] = {0,0,0,0,0,0};
    float maskO = 0.f;
    float xO[3]={0,0,0}, rO[3]={0,0,0}, uO[3]={0,0,0}, wO[3]={0,0,0}, mO[3]={0,0,0};
    float zO[3]={0,0,0}, qO[3]={0,0,0}, pO[3]={0,0,0}, sO[3]={0,0,0};
    if (ownval) {
        maskO = boundary[own] ? 0.f : 1.f;
        float s6[6];
#pragma unroll
        for (int j = 0; j < 6; j++) s6[j] = blk6[own*6 + j];
        float iv[6];
        sym_inv(s6, iv);
#pragma unroll
        for (int j = 0; j < 6; j++) iO[j] = iv[j] * maskO;
#pragma unroll
        for (int j = 0; j < 3; j++) rO[j] = bvec[3*own+j] * maskO;
        sym_apply(iO, rO, uO);
        vstore4(&mbuf[own*4], (f32x4){uO[0], uO[1], uO[2], 0.f});
    }
    flag_bar<true>(slots, 2);

    // ---- main loop ----
    unsigned tgt = 3;
    float gp = 1.f, ap = 1.f, stopv = 0.f;

    for (int k = 0; k <= NPH; k++) {
        float gam = 0.f, del = 0.f, beta = 0.f, alpha = 0.f;

        // top: reduce previous dots (all blocks identically); stop decision
        if (k >= 1) {
            if (threadIdx.x < 64) {
                const float* db = gdot + ((k - 1) & 1) * 48;
                float g = 0.f, d = 0.f, q = 0.f;
                if (lane < NBLK) {
                    g = aldf(&db[lane]);
                    d = aldf(&db[16 + lane]);
                    q = aldf(&db[32 + lane]);
                }
                bfly3w(g, d, q, 8);
                if (lane == 0) { sd[0] = g; sd[1] = d; sd[2] = q; }
            }
            __syncthreads();
            gam = sd[0]; del = sd[1];
            float rho = sd[2];
            if (k == 1) stopv = rho * 1e-8f;          // rel residual 1e-4
            else if (rho <= stopv) break;             // uniform across grid
            beta = (k == 1) ? 0.f : ((gp != 0.f) ? gam / gp : 0.f);
            float den = (k == 1) ? del : (del - beta * gam / ((ap != 0.f) ? ap : 1.f));
            alpha = (den != 0.f) ? gam / den : 0.f;
            __syncthreads();   // sd consumed before next iteration overwrites
        }

        // ===== A-phase: stage mbuf -> LDS, zero nacc, matvec, LDS-aggregate =====
        for (int i = threadIdx.x; i < N_NODES; i += NTHR) mstage[i] = vload4(&mbuf[i*4]);
        for (int i = threadIdx.x; i < 3 * N_NODES; i += NTHR) nacc[i] = 0.f;
        __syncthreads();
        {
            float pe[12];
#pragma unroll
            for (int kk = 0; kk < 4; kk++) {
                f32x4 mm = mstage[nd4[kk]];
                pe[3*kk] = mm[0]; pe[3*kk+1] = mm[1]; pe[3*kk+2] = mm[2];
            }
            float y[12];
            matvec(pe, y);
#pragma unroll
            for (int kk = 0; kk < 4; kk++) {
                atomicAdd(&nacc[nd4[kk]*3 + 0], y[3*kk]);
                atomicAdd(&nacc[nd4[kk]*3 + 1], y[3*kk+1]);
                atomicAdd(&nacc[nd4[kk]*3 + 2], y[3*kk+2]);
            }
        }
        __syncthreads();
        // coalesced partial write-out
        for (int i = threadIdx.x; i < N_NODES; i += NTHR) {
            f32x4 pv = { nacc[3*i], nacc[3*i+1], nacc[3*i+2], 0.f };
            vstore4(&pbuf[(blockIdx.x * N_NODES + i) * 4], pv);
        }
        flag_bar<false>(slots, tgt++);

        // ===== B-phase: owners gather partials + CG recurrences =====
        if (ownval) {
            f32x4 acc = {0.f, 0.f, 0.f, 0.f};
#pragma unroll
            for (int b = 0; b < NBLK; b++)
                acc += vload4(&pbuf[(b * N_NODES + own) * 4]);
            float n0 = acc[0] * maskO, n1 = acc[1] * maskO, n2 = acc[2] * maskO;

            if (k == 0) {
                wO[0] = n0; wO[1] = n1; wO[2] = n2;    // w0 = masked A u0
            } else {
                float nn[3] = {n0, n1, n2};
#pragma unroll
                for (int j = 0; j < 3; j++) {
                    zO[j] = nn[j] + beta * zO[j];
                    qO[j] = mO[j] + beta * qO[j];
                    pO[j] = uO[j] + beta * pO[j];
                    sO[j] = wO[j] + beta * sO[j];
                    xO[j] += alpha * pO[j];
                    rO[j] -= alpha * sO[j];
                    uO[j] -= alpha * qO[j];
                    wO[j] -= alpha * zO[j];
                }
            }
            sym_apply(iO, wO, mO);
            vstore4(&mbuf[own*4], (f32x4){mO[0], mO[1], mO[2], 0.f});

            float gn = 0.f, dn = 0.f, qn = 0.f;
#pragma unroll
            for (int j = 0; j < 3; j++) {
                gn += rO[j]*uO[j]; dn += wO[j]*uO[j]; qn += rO[j]*rO[j];
            }
            bfly3w(gn, dn, qn, 32);
            if (lane == 0) { sred[wv][0] = gn; sred[wv][1] = dn; sred[wv][2] = qn; }
        }
        __syncthreads();
        if (threadIdx.x == 0) {
            float* gpub = gdot + (k & 1) * 48;
            astf(&gpub[blockIdx.x],      sred[0][0] + sred[1][0]);
            astf(&gpub[16 + blockIdx.x], sred[0][1] + sred[1][1]);
            astf(&gpub[32 + blockIdx.x], sred[0][2] + sred[1][2]);
        }
        if (k >= 1) { gp = gam; ap = alpha; }
        flag_bar<false>(slots, tgt++);
    }

    if (ownval) {
#pragma unroll
        for (int j = 0; j < 3; j++) xout[3*own+j] = xO[j];
    }
}

extern "C" void kernel_launch(void* const* d_in, const int* in_sizes, int n_in,
                              void* d_out, int out_size, void* d_ws, size_t ws_size,
                              hipStream_t stream) {
    const float* theta = (const float*)d_in[0];
    const float* delta = (const float*)d_in[1];
    const float* ra    = (const float*)d_in[2];
    const float* rs    = (const float*)d_in[3];
    const float* rv    = (const float*)d_in[4];
    const float* vol   = (const float*)d_in[5];
    const float* b     = (const float*)d_in[6];
    const int* tets    = (const int*)d_in[7];
    const int* boundary = (const int*)d_in[8];
    float* x = (float*)d_out;
    float* ws = (float*)d_ws;

    hipMemsetAsync(ws, 0, WS_ZERO * sizeof(float), stream);
    pcg_kernel<<<dim3(NBLK), dim3(NTHR), 0, stream>>>(theta, delta, ra, rs, rv, vol, b,
                                                      tets, boundary, x, ws);
}

// Round 13
// 208.004 us; speedup vs baseline: 9.2685x; 1.5797x over previous
//
#include <hip/hip_runtime.h>

#define M_TETS 10240
#define N_NODES 2048
#define MAXPH 400
#define NBLK 32
#define NTHR 320
#define REP 4
#define SPIN_CAP 50000000

// ws float offsets
#define BUFW  (REP * N_NODES * 4)         // 32768 floats per rotating buffer
#define OFF_VAL   12288                   // blk6: 6*2048 floats at 0
#define OFF_GDOT  (OFF_VAL + 3 * BUFW)    // 12288 + 98304 = 110592
#define OFF_SLOT  (OFF_GDOT + 384)        // 2 sets x 3 comps x 64
#define WS_WORDS  (OFF_SLOT + 32)

// log(500), log(10000)
__device__ __constant__ float LOG_A_MIN_C = 6.2146080984221914f;
__device__ __constant__ float LOG_A_MAX_C = 9.2103403719761836f;

__device__ __forceinline__ void rel_fence() { __builtin_amdgcn_fence(__ATOMIC_RELEASE, "agent"); }
__device__ __forceinline__ void acq_fence() { __builtin_amdgcn_fence(__ATOMIC_ACQUIRE, "agent"); }
__device__ __forceinline__ unsigned aldu(const unsigned* p) {
    return __hip_atomic_load(p, __ATOMIC_RELAXED, __HIP_MEMORY_SCOPE_AGENT);
}
__device__ __forceinline__ float aldf(const float* p) {
    return __hip_atomic_load(p, __ATOMIC_RELAXED, __HIP_MEMORY_SCOPE_AGENT);
}
__device__ __forceinline__ void astf(float* p, float v) {
    __hip_atomic_store(p, v, __ATOMIC_RELAXED, __HIP_MEMORY_SCOPE_AGENT);
}
__device__ __forceinline__ void astu(unsigned* p, unsigned v) {
    __hip_atomic_store(p, v, __ATOMIC_RELAXED, __HIP_MEMORY_SCOPE_AGENT);
}

// Distributed-flag barrier: one publish per block, 32-lane parallel poll.
__device__ __forceinline__ void flag_bar(unsigned* slots, unsigned tgt) {
    rel_fence();
    __syncthreads();
    if (threadIdx.x == 0) astu(&slots[blockIdx.x], tgt);
    if (threadIdx.x < NBLK) {
        int guard = 0;
        while (aldu(&slots[threadIdx.x]) < tgt && ++guard < SPIN_CAP) {}
    }
    __syncthreads();
    acq_fence();
}

__device__ __forceinline__ void bfly3(float& a, float& b, float& c) {
#pragma unroll
    for (int off = 32; off > 0; off >>= 1) {
        a += __shfl_xor(a, off);
        b += __shfl_xor(b, off);
        c += __shfl_xor(c, off);
    }
}

// symmetric 3x3 apply: s6 = [00,01,02,11,12,22]
__device__ __forceinline__ void sym_apply(const float* s6, const float* v, float* out) {
    out[0] = s6[0]*v[0] + s6[1]*v[1] + s6[2]*v[2];
    out[1] = s6[1]*v[0] + s6[3]*v[1] + s6[4]*v[2];
    out[2] = s6[2]*v[0] + s6[4]*v[1] + s6[5]*v[2];
}

__device__ __forceinline__ void sym_inv(const float* s, float* o) {
    float a = s[0], b = s[1], c = s[2], d = s[3], e = s[4], f = s[5];
    float C00 = d*f - e*e, C01 = c*e - b*f, C02 = b*e - c*d;
    float id = 1.0f / (a*C00 + b*C01 + c*C02);
    o[0] = C00*id; o[1] = C01*id; o[2] = C02*id;
    o[3] = (a*f - c*c)*id; o[4] = (b*c - a*e)*id; o[5] = (a*d - b*b)*id;
}

__global__ void __launch_bounds__(NTHR, 1) pcg_kernel(
    const float* __restrict__ theta, const float* __restrict__ delta,
    const float* __restrict__ ra, const float* __restrict__ rs, const float* __restrict__ rv,
    const float* __restrict__ vol, const float* __restrict__ bvec,
    const int* __restrict__ tets, const int* __restrict__ boundary,
    float* __restrict__ xout, float* __restrict__ ws)
{
    const int tid = blockIdx.x * NTHR + threadIdx.x;   // element id, 10240 total
    const int lane = threadIdx.x & 63;
    __shared__ float sd[3];

    float*    blk6  = ws;
    float*    val   = ws + OFF_VAL;
    float*    gdot  = ws + OFF_GDOT;
    unsigned* slots = (unsigned*)(ws + OFF_SLOT);

    // ---- element data -> registers (ws pre-zeroed by hipMemsetAsync) ----
    float A[3][12], S[3][12], V[12];
    int nd4[4];
    float cae, cse, cve;
    {
        const int e = tid;
#pragma unroll
        for (int a = 0; a < 3; a++)
#pragma unroll
            for (int i = 0; i < 12; i++) {
                A[a][i] = ra[e * 36 + a * 12 + i];
                S[a][i] = rs[e * 36 + a * 12 + i];
            }
#pragma unroll
        for (int i = 0; i < 12; i++) V[i] = rv[e * 12 + i];
        const int4 t = reinterpret_cast<const int4*>(tets)[e];
        nd4[0] = t.x; nd4[1] = t.y; nd4[2] = t.z; nd4[3] = t.w;
        float la = theta[0] + delta[e];
        la = fminf(fmaxf(la, LOG_A_MIN_C), LOG_A_MAX_C);
        float al = expf(la);
        float v = vol[e];
        cae = v * al; cse = 2.0f * v * al; cve = 8.0f * v * al;
    }
    const int myrep = (tid & (REP - 1)) * (N_NODES * 4);   // this element's replica offset

    auto matvec = [&](const float* pe, float* y) {
#pragma unroll
        for (int t = 0; t < 12; t++) y[t] = 0.f;
#pragma unroll
        for (int a = 0; a < 3; a++) {
            float qa = 0.f, qs = 0.f;
#pragma unroll
            for (int t = 0; t < 12; t++) { qa += A[a][t] * pe[t]; qs += S[a][t] * pe[t]; }
            qa *= cae; qs *= cse;
#pragma unroll
            for (int t = 0; t < 12; t++) y[t] += qa * A[a][t] + qs * S[a][t];
        }
        float qv = 0.f;
#pragma unroll
        for (int t = 0; t < 12; t++) qv += V[t] * pe[t];
        qv *= cve;
#pragma unroll
        for (int t = 0; t < 12; t++) y[t] += qv * V[t];
    };

    // gather a node-vector (sum over replicas) for this element's 4 nodes
    auto gather4 = [&](const float* vR, float* ne, const float* nmask4) {
#pragma unroll
        for (int kk = 0; kk < 4; kk++) {
            float s0 = 0.f, s1 = 0.f, s2 = 0.f;
#pragma unroll
            for (int r = 0; r < REP; r++) {
                float4 t = *reinterpret_cast<const float4*>(&vR[r * (N_NODES*4) + 4*nd4[kk]]);
                s0 += t.x; s1 += t.y; s2 += t.z;
            }
            ne[3*kk]   = s0 * nmask4[kk];
            ne[3*kk+1] = s1 * nmask4[kk];
            ne[3*kk+2] = s2 * nmask4[kk];
        }
    };

    // ---- S1: accumulate symmetric per-node 3x3 blocks of K ----
#pragma unroll
    for (int k = 0; k < 4; k++) {
        float b6[6] = {0,0,0,0,0,0};
#pragma unroll
        for (int a = 0; a < 3; a++) {
            float x0 = A[a][3*k], x1 = A[a][3*k+1], x2 = A[a][3*k+2];
            float s0 = S[a][3*k], s1 = S[a][3*k+1], s2 = S[a][3*k+2];
            b6[0] += cae*x0*x0 + cse*s0*s0;
            b6[1] += cae*x0*x1 + cse*s0*s1;
            b6[2] += cae*x0*x2 + cse*s0*s2;
            b6[3] += cae*x1*x1 + cse*s1*s1;
            b6[4] += cae*x1*x2 + cse*s1*s2;
            b6[5] += cae*x2*x2 + cse*s2*s2;
        }
        float v0 = V[3*k], v1 = V[3*k+1], v2 = V[3*k+2];
        b6[0] += cve*v0*v0; b6[1] += cve*v0*v1; b6[2] += cve*v0*v2;
        b6[3] += cve*v1*v1; b6[4] += cve*v1*v2; b6[5] += cve*v2*v2;
#pragma unroll
        for (int j = 0; j < 6; j++) atomicAdd(&blk6[nd4[k]*6 + j], b6[j]);
    }
    flag_bar(slots, 1);

    // ---- local inverses: elements (masked, per node) and owners ----
    float ib[4][6], nmask4[4];
#pragma unroll
    for (int k = 0; k < 4; k++) {
        float bm = boundary[nd4[k]] ? 0.f : 1.f;
        nmask4[k] = bm;
        float s6[6];
#pragma unroll
        for (int j = 0; j < 6; j++) s6[j] = blk6[nd4[k]*6 + j];
        float iv[6];
        sym_inv(s6, iv);
#pragma unroll
        for (int j = 0; j < 6; j++) ib[k][j] = iv[j] * bm;
    }

    const int own = blockIdx.x * 64 + threadIdx.x;   // exact: 32*64 = 2048
    const bool ownval = (threadIdx.x < 64);
    float iO[6] = {0,0,0,0,0,0};
    float maskO = 0.f;
    float xO[3]={0,0,0}, rO[3]={0,0,0}, uO[3]={0,0,0}, wO[3]={0,0,0}, mO[3]={0,0,0};
    float zO[3]={0,0,0}, qO[3]={0,0,0}, pO[3]={0,0,0}, sO[3]={0,0,0};
    if (ownval) {
        maskO = boundary[own] ? 0.f : 1.f;
        float s6[6];
#pragma unroll
        for (int j = 0; j < 6; j++) s6[j] = blk6[own*6 + j];
        float iv[6];
        sym_inv(s6, iv);
#pragma unroll
        for (int j = 0; j < 6; j++) iO[j] = iv[j] * maskO;
#pragma unroll
        for (int j = 0; j < 3; j++) rO[j] = bvec[3*own+j] * maskO;
        sym_apply(iO, rO, uO);
    }

    // ---- phase -1: scatter A*u0 into buf2 (own replica) ----
    {
        float u0e[12];
#pragma unroll
        for (int k = 0; k < 4; k++) {
            float bb[3] = { bvec[3*nd4[k]], bvec[3*nd4[k]+1], bvec[3*nd4[k]+2] };
            sym_apply(ib[k], bb, &u0e[3*k]);
        }
        float y[12];
        matvec(u0e, y);
        float* v2 = val + 2 * BUFW + myrep;
#pragma unroll
        for (int kk = 0; kk < 4; kk++)
#pragma unroll
            for (int c = 0; c < 3; c++) atomicAdd(&v2[4*nd4[kk]+c], y[3*kk+c]);
    }
    flag_bar(slots, 2);

    // ---- phase 0: consume buf2 (w0); init replicas/owner; scatter A*m0 -> buf0; dots(0) ----
    float w_e[12], z_e[12];
    {
        const float* vR = val + 2 * BUFW;
        gather4(vR, w_e, nmask4);
#pragma unroll
        for (int t = 0; t < 12; t++) z_e[t] = 0.f;
        float me[12];
#pragma unroll
        for (int kk = 0; kk < 4; kk++) sym_apply(ib[kk], &w_e[3*kk], &me[3*kk]);
        float y[12];
        matvec(me, y);
        float* vS = val + myrep;   // buf0
#pragma unroll
        for (int kk = 0; kk < 4; kk++)
#pragma unroll
            for (int c = 0; c < 3; c++) atomicAdd(&vS[4*nd4[kk]+c], y[3*kk+c]);

        if (ownval) {
            float gn = 0.f, dn = 0.f, qn = 0.f;
            float s0 = 0.f, s1 = 0.f, s2 = 0.f;
#pragma unroll
            for (int r = 0; r < REP; r++) {
                float4 t = *reinterpret_cast<const float4*>(&vR[r * (N_NODES*4) + 4*own]);
                s0 += t.x; s1 += t.y; s2 += t.z;
            }
            wO[0] = s0 * maskO; wO[1] = s1 * maskO; wO[2] = s2 * maskO;
            sym_apply(iO, wO, mO);
#pragma unroll
            for (int j = 0; j < 3; j++) {
                gn += rO[j]*uO[j]; dn += wO[j]*uO[j]; qn += rO[j]*rO[j];
            }
            bfly3(gn, dn, qn);
            if (threadIdx.x == 0) {
                astf(&gdot[blockIdx.x], gn);
                astf(&gdot[64 + blockIdx.x], dn);
                astf(&gdot[128 + blockIdx.x], qn);
            }
        }
    }
    flag_bar(slots, 3);

    // ---- main loop: one phase, one barrier per iteration ----
    int rd = 0, sc = 1, ze = 2;
    float gp = 1.f, ap = 1.f, stop = 0.f;
    unsigned tgt = 4;

    for (int k = 1; k <= MAXPH; k++) {
        const float* vR = val + rd * BUFW;

        // gather n early (overlaps dot completion)
        float ne[12];
        gather4(vR, ne, nmask4);
        float nO[3] = {0,0,0};
        if (ownval) {
            float s0 = 0.f, s1 = 0.f, s2 = 0.f;
#pragma unroll
            for (int r = 0; r < REP; r++) {
                float4 t = *reinterpret_cast<const float4*>(&vR[r * (N_NODES*4) + 4*own]);
                s0 += t.x; s1 += t.y; s2 += t.z;
            }
            nO[0] = s0 * maskO; nO[1] = s1 * maskO; nO[2] = s2 * maskO;
        }

        // cross-block dot completion (wave 0; slots 32..63 are zero-padding)
        if (threadIdx.x < 64) {
            const float* dbase = gdot + ((k - 1) & 1) * 192;
            float g0 = aldf(&dbase[lane]);
            float d0 = aldf(&dbase[64 + lane]);
            float q0 = aldf(&dbase[128 + lane]);
            bfly3(g0, d0, q0);
            if (threadIdx.x == 0) { sd[0] = g0; sd[1] = d0; sd[2] = q0; }
        }
        __syncthreads();
        float gam = sd[0], del = sd[1], rho = sd[2];

        if (k == 1) stop = rho * 4e-8f;      // rel residual 2e-4
        else if (rho <= stop) break;         // uniform across grid
        float beta  = (k == 1) ? 0.f : ((gp != 0.f) ? gam / gp : 0.f);
        float den   = (k == 1) ? del : (del - beta * gam / ((ap != 0.f) ? ap : 1.f));
        float alpha = (den != 0.f) ? gam / den : 0.f;

        // element replica update + matvec + scatter into buffer sc (own replica)
        {
#pragma unroll
            for (int t = 0; t < 12; t++) {
                z_e[t] = ne[t] + beta * z_e[t];
                w_e[t] -= alpha * z_e[t];
            }
            float me[12];
#pragma unroll
            for (int kk = 0; kk < 4; kk++) sym_apply(ib[kk], &w_e[3*kk], &me[3*kk]);
            float y[12];
            matvec(me, y);
            float* vS = val + sc * BUFW + myrep;
#pragma unroll
            for (int kk = 0; kk < 4; kk++)
#pragma unroll
                for (int c = 0; c < 3; c++) atomicAdd(&vS[4*nd4[kk]+c], y[3*kk+c]);
        }

        // owner recurrences + dot publish + zero buffer ze (all replicas)
        if (ownval) {
            float gn = 0.f, dn = 0.f, qn = 0.f;
#pragma unroll
            for (int j = 0; j < 3; j++) {
                zO[j] = nO[j] + beta * zO[j];
                qO[j] = mO[j] + beta * qO[j];
                pO[j] = uO[j] + beta * pO[j];
                sO[j] = wO[j] + beta * sO[j];
                xO[j] += alpha * pO[j];
                rO[j] -= alpha * sO[j];
                uO[j] -= alpha * qO[j];
                wO[j] -= alpha * zO[j];
            }
            sym_apply(iO, wO, mO);
#pragma unroll
            for (int j = 0; j < 3; j++) {
                gn += rO[j]*uO[j]; dn += wO[j]*uO[j]; qn += rO[j]*rO[j];
            }
            bfly3(gn, dn, qn);
            float* gd_pub = gdot + (k & 1) * 192;
            if (threadIdx.x == 0) {
                astf(&gd_pub[blockIdx.x], gn);
                astf(&gd_pub[64 + blockIdx.x], dn);
                astf(&gd_pub[128 + blockIdx.x], qn);
            }
            float* vZ = val + ze * BUFW;
#pragma unroll
            for (int r = 0; r < REP; r++) {
                astf(&vZ[r * (N_NODES*4) + 4*own + 0], 0.f);
                astf(&vZ[r * (N_NODES*4) + 4*own + 1], 0.f);
                astf(&vZ[r * (N_NODES*4) + 4*own + 2], 0.f);
            }
        }

        gp = gam; ap = alpha;
        flag_bar(slots, tgt++);
        int t2 = rd; rd = sc; sc = ze; ze = t2;
    }

    if (ownval) {
#pragma unroll
        for (int j = 0; j < 3; j++) xout[3*own+j] = xO[j];
    }

    // publish m (owners already did via mO->? not needed; mbuf not used in this variant)
}

extern "C" void kernel_launch(void* const* d_in, const int* in_sizes, int n_in,
                              void* d_out, int out_size, void* d_ws, size_t ws_size,
                              hipStream_t stream) {
    const float* theta = (const float*)d_in[0];
    const float* delta = (const float*)d_in[1];
    const float* ra    = (const float*)d_in[2];
    const float* rs    = (const float*)d_in[3];
    const float* rv    = (const float*)d_in[4];
    const float* vol   = (const float*)d_in[5];
    const float* b     = (const float*)d_in[6];
    const int* tets    = (const int*)d_in[7];
    const int* boundary = (const int*)d_in[8];
    float* x = (float*)d_out;
    float* ws = (float*)d_ws;

    hipMemsetAsync(ws, 0, WS_WORDS * sizeof(float), stream);
    pcg_kernel<<<dim3(NBLK), dim3(NTHR), 0, stream>>>(theta, delta, ra, rs, rv, vol, b,
                                                      tets, boundary, x, ws);
}

// Round 14
// 160.596 us; speedup vs baseline: 12.0045x; 1.2952x over previous
//
#include <hip/hip_runtime.h>

#define M_TETS 10240
#define N_NODES 2048
#define MAXPH 400
#define NBLK 32
#define NTHR 320
#define SPIN_CAP 50000000

typedef float f32x4 __attribute__((ext_vector_type(4)));

// ws float offsets
#define OFF_VAL   12288            // blk6: 6*2048 floats at 0
#define OFF_GDOT  36864            // val: 3 bufs x 2048 x 4
#define OFF_SLOT  37248            // gdot: 2 sets x 3 x 64
#define WS_WORDS  37280            // + 32 flag words

// log(500), log(10000)
__device__ __constant__ float LOG_A_MIN_C = 6.2146080984221914f;
__device__ __constant__ float LOG_A_MAX_C = 9.2103403719761836f;

__device__ __forceinline__ void rel_fence() { __builtin_amdgcn_fence(__ATOMIC_RELEASE, "agent"); }
__device__ __forceinline__ void acq_fence() { __builtin_amdgcn_fence(__ATOMIC_ACQUIRE, "agent"); }
__device__ __forceinline__ unsigned aldu(const unsigned* p) {
    return __hip_atomic_load(p, __ATOMIC_RELAXED, __HIP_MEMORY_SCOPE_AGENT);
}
__device__ __forceinline__ float aldf(const float* p) {
    return __hip_atomic_load(p, __ATOMIC_RELAXED, __HIP_MEMORY_SCOPE_AGENT);
}
__device__ __forceinline__ void astf(float* p, float v) {
    __hip_atomic_store(p, v, __ATOMIC_RELAXED, __HIP_MEMORY_SCOPE_AGENT);
}
__device__ __forceinline__ void astu(unsigned* p, unsigned v) {
    __hip_atomic_store(p, v, __ATOMIC_RELAXED, __HIP_MEMORY_SCOPE_AGENT);
}

// coherence-point 16B load (R12-proven: volatile vector load observes remote
// agent-atomic stores across XCDs with no fences)
__device__ __forceinline__ f32x4 vload4(const float* p) {
    return *(volatile const f32x4*)p;
}

// Flag barrier. FULL=true: full release/acquire fences (setup only).
// FULL=false: fence-free — in-loop writes are all agent atomics (performed at
// the coherence point); release ordering = s_waitcnt vmcnt(0) before the flag
// store; reads after the barrier use volatile/atomic ops, so no inv needed.
template<bool FULL>
__device__ __forceinline__ void flag_bar(unsigned* slots, unsigned tgt) {
    if (FULL) rel_fence();
    else asm volatile("s_waitcnt vmcnt(0)" ::: "memory");
    __syncthreads();
    if (threadIdx.x == 0) astu(&slots[blockIdx.x], tgt);
    if (threadIdx.x < NBLK) {
        int guard = 0;
        while (aldu(&slots[threadIdx.x]) < tgt && ++guard < SPIN_CAP) {}
    }
    __syncthreads();
    if (FULL) acq_fence();
    else asm volatile("" ::: "memory");
}

__device__ __forceinline__ void bfly3(float& a, float& b, float& c) {
#pragma unroll
    for (int off = 32; off > 0; off >>= 1) {
        a += __shfl_xor(a, off);
        b += __shfl_xor(b, off);
        c += __shfl_xor(c, off);
    }
}

// symmetric 3x3 apply: s6 = [00,01,02,11,12,22]
__device__ __forceinline__ void sym_apply(const float* s6, const float* v, float* out) {
    out[0] = s6[0]*v[0] + s6[1]*v[1] + s6[2]*v[2];
    out[1] = s6[1]*v[0] + s6[3]*v[1] + s6[4]*v[2];
    out[2] = s6[2]*v[0] + s6[4]*v[1] + s6[5]*v[2];
}

__device__ __forceinline__ void sym_inv(const float* s, float* o) {
    float a = s[0], b = s[1], c = s[2], d = s[3], e = s[4], f = s[5];
    float C00 = d*f - e*e, C01 = c*e - b*f, C02 = b*e - c*d;
    float id = 1.0f / (a*C00 + b*C01 + c*C02);
    o[0] = C00*id; o[1] = C01*id; o[2] = C02*id;
    o[3] = (a*f - c*c)*id; o[4] = (b*c - a*e)*id; o[5] = (a*d - b*b)*id;
}

__global__ void __launch_bounds__(NTHR, 1) pcg_kernel(
    const float* __restrict__ theta, const float* __restrict__ delta,
    const float* __restrict__ ra, const float* __restrict__ rs, const float* __restrict__ rv,
    const float* __restrict__ vol, const float* __restrict__ bvec,
    const int* __restrict__ tets, const int* __restrict__ boundary,
    float* __restrict__ xout, float* __restrict__ ws)
{
    const int tid = blockIdx.x * NTHR + threadIdx.x;   // element id, 10240 total
    const int lane = threadIdx.x & 63;
    __shared__ float sd[3];

    float*    blk6  = ws;
    float*    val   = ws + OFF_VAL;
    float*    gdot  = ws + OFF_GDOT;
    unsigned* slots = (unsigned*)(ws + OFF_SLOT);

    // ---- element data -> registers (ws pre-zeroed by hipMemsetAsync) ----
    float A[3][12], S[3][12], V[12];
    int nd4[4];
    float cae, cse, cve;
    {
        const int e = tid;
#pragma unroll
        for (int a = 0; a < 3; a++)
#pragma unroll
            for (int i = 0; i < 12; i++) {
                A[a][i] = ra[e * 36 + a * 12 + i];
                S[a][i] = rs[e * 36 + a * 12 + i];
            }
#pragma unroll
        for (int i = 0; i < 12; i++) V[i] = rv[e * 12 + i];
        const int4 t = reinterpret_cast<const int4*>(tets)[e];
        nd4[0] = t.x; nd4[1] = t.y; nd4[2] = t.z; nd4[3] = t.w;
        float la = theta[0] + delta[e];
        la = fminf(fmaxf(la, LOG_A_MIN_C), LOG_A_MAX_C);
        float al = expf(la);
        float v = vol[e];
        cae = v * al; cse = 2.0f * v * al; cve = 8.0f * v * al;
    }

    auto matvec = [&](const float* pe, float* y) {
#pragma unroll
        for (int t = 0; t < 12; t++) y[t] = 0.f;
#pragma unroll
        for (int a = 0; a < 3; a++) {
            float qa = 0.f, qs = 0.f;
#pragma unroll
            for (int t = 0; t < 12; t++) { qa += A[a][t] * pe[t]; qs += S[a][t] * pe[t]; }
            qa *= cae; qs *= cse;
#pragma unroll
            for (int t = 0; t < 12; t++) y[t] += qa * A[a][t] + qs * S[a][t];
        }
        float qv = 0.f;
#pragma unroll
        for (int t = 0; t < 12; t++) qv += V[t] * pe[t];
        qv *= cve;
#pragma unroll
        for (int t = 0; t < 12; t++) y[t] += qv * V[t];
    };

    // ---- S1: accumulate symmetric per-node 3x3 blocks of K ----
#pragma unroll
    for (int k = 0; k < 4; k++) {
        float b6[6] = {0,0,0,0,0,0};
#pragma unroll
        for (int a = 0; a < 3; a++) {
            float x0 = A[a][3*k], x1 = A[a][3*k+1], x2 = A[a][3*k+2];
            float s0 = S[a][3*k], s1 = S[a][3*k+1], s2 = S[a][3*k+2];
            b6[0] += cae*x0*x0 + cse*s0*s0;
            b6[1] += cae*x0*x1 + cse*s0*s1;
            b6[2] += cae*x0*x2 + cse*s0*s2;
            b6[3] += cae*x1*x1 + cse*s1*s1;
            b6[4] += cae*x1*x2 + cse*s1*s2;
            b6[5] += cae*x2*x2 + cse*s2*s2;
        }
        float v0 = V[3*k], v1 = V[3*k+1], v2 = V[3*k+2];
        b6[0] += cve*v0*v0; b6[1] += cve*v0*v1; b6[2] += cve*v0*v2;
        b6[3] += cve*v1*v1; b6[4] += cve*v1*v2; b6[5] += cve*v2*v2;
#pragma unroll
        for (int j = 0; j < 6; j++) atomicAdd(&blk6[nd4[k]*6 + j], b6[j]);
    }
    flag_bar<true>(slots, 1);

    // ---- local inverses: elements (masked, per node) and owners ----
    float ib[4][6], nmask4[4];
#pragma unroll
    for (int k = 0; k < 4; k++) {
        float bm = boundary[nd4[k]] ? 0.f : 1.f;
        nmask4[k] = bm;
        float s6[6];
#pragma unroll
        for (int j = 0; j < 6; j++) s6[j] = blk6[nd4[k]*6 + j];
        float iv[6];
        sym_inv(s6, iv);
#pragma unroll
        for (int j = 0; j < 6; j++) ib[k][j] = iv[j] * bm;
    }

    const int own = blockIdx.x * 64 + threadIdx.x;   // exact: 32*64 = 2048
    const bool ownval = (threadIdx.x < 64);
    float iO[6] = {0,0,0,0,0,0};
    float maskO = 0.f;
    float xO[3]={0,0,0}, rO[3]={0,0,0}, uO[3]={0,0,0}, wO[3]={0,0,0}, mO[3]={0,0,0};
    float zO[3]={0,0,0}, qO[3]={0,0,0}, pO[3]={0,0,0}, sO[3]={0,0,0};
    if (ownval) {
        maskO = boundary[own] ? 0.f : 1.f;
        float s6[6];
#pragma unroll
        for (int j = 0; j < 6; j++) s6[j] = blk6[own*6 + j];
        float iv[6];
        sym_inv(s6, iv);
#pragma unroll
        for (int j = 0; j < 6; j++) iO[j] = iv[j] * maskO;
#pragma unroll
        for (int j = 0; j < 3; j++) rO[j] = bvec[3*own+j] * maskO;
        sym_apply(iO, rO, uO);
    }

    // ---- phase -1: scatter A*u0 into buf2 ----
    {
        float u0e[12];
#pragma unroll
        for (int k = 0; k < 4; k++) {
            float bb[3] = { bvec[3*nd4[k]], bvec[3*nd4[k]+1], bvec[3*nd4[k]+2] };
            sym_apply(ib[k], bb, &u0e[3*k]);
        }
        float y[12];
        matvec(u0e, y);
        float* v2 = val + 2 * 8192;
#pragma unroll
        for (int kk = 0; kk < 4; kk++)
#pragma unroll
            for (int c = 0; c < 3; c++) atomicAdd(&v2[4*nd4[kk]+c], y[3*kk+c]);
    }
    flag_bar<false>(slots, 2);

    // ---- phase 0: consume buf2 (w0); init replicas/owner; scatter A*m0 -> buf0; dots(0) ----
    float w_e[12], z_e[12];
    {
        const float* vR = val + 2 * 8192;
#pragma unroll
        for (int kk = 0; kk < 4; kk++) {
            f32x4 t = vload4(&vR[4*nd4[kk]]);
            w_e[3*kk]   = t[0] * nmask4[kk];
            w_e[3*kk+1] = t[1] * nmask4[kk];
            w_e[3*kk+2] = t[2] * nmask4[kk];
            z_e[3*kk] = 0.f; z_e[3*kk+1] = 0.f; z_e[3*kk+2] = 0.f;
        }
        float me[12];
#pragma unroll
        for (int kk = 0; kk < 4; kk++) sym_apply(ib[kk], &w_e[3*kk], &me[3*kk]);
        float y[12];
        matvec(me, y);
        float* vS = val;   // buf0
#pragma unroll
        for (int kk = 0; kk < 4; kk++)
#pragma unroll
            for (int c = 0; c < 3; c++) atomicAdd(&vS[4*nd4[kk]+c], y[3*kk+c]);

        if (ownval) {
            float gn = 0.f, dn = 0.f, qn = 0.f;
            f32x4 t = vload4(&vR[4*own]);
            wO[0] = t[0] * maskO; wO[1] = t[1] * maskO; wO[2] = t[2] * maskO;
            sym_apply(iO, wO, mO);
#pragma unroll
            for (int j = 0; j < 3; j++) {
                gn += rO[j]*uO[j]; dn += wO[j]*uO[j]; qn += rO[j]*rO[j];
            }
            bfly3(gn, dn, qn);
            if (threadIdx.x == 0) {
                astf(&gdot[blockIdx.x], gn);
                astf(&gdot[64 + blockIdx.x], dn);
                astf(&gdot[128 + blockIdx.x], qn);
            }
        }
    }
    flag_bar<false>(slots, 3);

    // ---- main loop: one phase, one fence-free barrier per iteration ----
    int rd = 0, sc = 1, ze = 2;
    float gp = 1.f, ap = 1.f, stop = 0.f;
    unsigned tgt = 4;

    for (int k = 1; k <= MAXPH; k++) {
        const float* vR = val + rd * 8192;

        // gather n early (volatile -> coherence point; overlaps dot completion)
        float ne[12];
#pragma unroll
        for (int kk = 0; kk < 4; kk++) {
            f32x4 t = vload4(&vR[4*nd4[kk]]);
            ne[3*kk]   = t[0] * nmask4[kk];
            ne[3*kk+1] = t[1] * nmask4[kk];
            ne[3*kk+2] = t[2] * nmask4[kk];
        }
        float nO[3] = {0,0,0};
        if (ownval) {
            f32x4 t = vload4(&vR[4*own]);
            nO[0] = t[0] * maskO; nO[1] = t[1] * maskO; nO[2] = t[2] * maskO;
        }

        // cross-block dot completion (wave 0; slots 32..63 are zero-padding)
        if (threadIdx.x < 64) {
            const float* dbase = gdot + ((k - 1) & 1) * 192;
            float g0 = aldf(&dbase[lane]);
            float d0 = aldf(&dbase[64 + lane]);
            float q0 = aldf(&dbase[128 + lane]);
            bfly3(g0, d0, q0);
            if (threadIdx.x == 0) { sd[0] = g0; sd[1] = d0; sd[2] = q0; }
        }
        __syncthreads();
        float gam = sd[0], del = sd[1], rho = sd[2];

        if (k == 1) stop = rho * 4e-8f;      // rel residual 2e-4
        else if (rho <= stop) break;         // uniform across grid
        float beta  = (k == 1) ? 0.f : ((gp != 0.f) ? gam / gp : 0.f);
        float den   = (k == 1) ? del : (del - beta * gam / ((ap != 0.f) ? ap : 1.f));
        float alpha = (den != 0.f) ? gam / den : 0.f;

        // element replica update + matvec + scatter into buffer sc
        {
#pragma unroll
            for (int t = 0; t < 12; t++) {
                z_e[t] = ne[t] + beta * z_e[t];
                w_e[t] -= alpha * z_e[t];
            }
            float me[12];
#pragma unroll
            for (int kk = 0; kk < 4; kk++) sym_apply(ib[kk], &w_e[3*kk], &me[3*kk]);
            float y[12];
            matvec(me, y);
            float* vS = val + sc * 8192;
#pragma unroll
            for (int kk = 0; kk < 4; kk++)
#pragma unroll
                for (int c = 0; c < 3; c++) atomicAdd(&vS[4*nd4[kk]+c], y[3*kk+c]);
        }

        // owner recurrences + dot publish + zero buffer ze
        if (ownval) {
            float gn = 0.f, dn = 0.f, qn = 0.f;
#pragma unroll
            for (int j = 0; j < 3; j++) {
                zO[j] = nO[j] + beta * zO[j];
                qO[j] = mO[j] + beta * qO[j];
                pO[j] = uO[j] + beta * pO[j];
                sO[j] = wO[j] + beta * sO[j];
                xO[j] += alpha * pO[j];
                rO[j] -= alpha * sO[j];
                uO[j] -= alpha * qO[j];
                wO[j] -= alpha * zO[j];
            }
            sym_apply(iO, wO, mO);
#pragma unroll
            for (int j = 0; j < 3; j++) {
                gn += rO[j]*uO[j]; dn += wO[j]*uO[j]; qn += rO[j]*rO[j];
            }
            bfly3(gn, dn, qn);
            float* gd_pub = gdot + (k & 1) * 192;
            if (threadIdx.x == 0) {
                astf(&gd_pub[blockIdx.x], gn);
                astf(&gd_pub[64 + blockIdx.x], dn);
                astf(&gd_pub[128 + blockIdx.x], qn);
            }
            float* vZ = val + ze * 8192;
            astf(&vZ[4*own+0], 0.f); astf(&vZ[4*own+1], 0.f);
            astf(&vZ[4*own+2], 0.f); astf(&vZ[4*own+3], 0.f);
        }

        gp = gam; ap = alpha;
        flag_bar<false>(slots, tgt++);
        int t2 = rd; rd = sc; sc = ze; ze = t2;
    }

    if (ownval) {
#pragma unroll
        for (int j = 0; j < 3; j++) xout[3*own+j] = xO[j];
    }
}

extern "C" void kernel_launch(void* const* d_in, const int* in_sizes, int n_in,
                              void* d_out, int out_size, void* d_ws, size_t ws_size,
                              hipStream_t stream) {
    const float* theta = (const float*)d_in[0];
    const float* delta = (const float*)d_in[1];
    const float* ra    = (const float*)d_in[2];
    const float* rs    = (const float*)d_in[3];
    const float* rv    = (const float*)d_in[4];
    const float* vol   = (const float*)d_in[5];
    const float* b     = (const float*)d_in[6];
    const int* tets    = (const int*)d_in[7];
    const int* boundary = (const int*)d_in[8];
    float* x = (float*)d_out;
    float* ws = (float*)d_ws;

    hipMemsetAsync(ws, 0, WS_WORDS * sizeof(float), stream);
    pcg_kernel<<<dim3(NBLK), dim3(NTHR), 0, stream>>>(theta, delta, ra, rs, rv, vol, b,
                                                      tets, boundary, x, ws);
}